// Round 10
// baseline (1555.212 us; speedup 1.0000x reference)
//
#include <hip/hip_runtime.h>
#include <cstdint>
#include <cmath>

#define HW48 2304   // 48*48 positions
#define F9   2304   // 256*9 features

typedef _Float16 half8_t __attribute__((ext_vector_type(8)));
typedef float floatx4 __attribute__((ext_vector_type(4)));

// async global->LDS, 16 B per lane, wave-uniform LDS base + lane*16
__device__ __forceinline__ void gl2lds16(const _Float16* g, _Float16* l) {
  __builtin_amdgcn_global_load_lds((const __attribute__((address_space(1))) void*)g,
                                   (__attribute__((address_space(3))) void*)l,
                                   16, 0, 0);
}

// insert (v,row) into 5-list sorted by (val desc, row asc) — jax top_k order
__device__ __forceinline__ void insert5(float v, int row, float* tv, int* tr) {
  if (v > tv[4] || (v == tv[4] && row < tr[4])) {
    int k = 4;
    while (k > 0 && (v > tv[k - 1] || (v == tv[k - 1] && row < tr[k - 1]))) {
      tv[k] = tv[k - 1]; tr[k] = tr[k - 1]; --k;
    }
    tv[k] = v; tr[k] = row;
  }
}

// ---------------- pos-encode: dst = src + conv3x3(posgrid) ----------------
__global__ void enc_kernel(const float* __restrict__ src, const float* __restrict__ w,
                           const float* __restrict__ b, float* __restrict__ dst,
                           int C, int H, int ms, int total) {
  int idx = blockIdx.x * blockDim.x + threadIdx.x;
  if (idx >= total) return;
  int x = idx % H;
  int y = (idx / H) % H;
  int c = (idx / (H * H)) % C;
  float scale = (float)((double)ms / (double)H);
  float msm1 = (float)(ms - 1);
  float conv = b[c];
#pragma unroll
  for (int dy = 0; dy < 3; ++dy) {
    int yy = y + dy - 1;
    if (yy < 0 || yy >= H) continue;
    float sy = fminf(fmaxf((yy + 0.5f) * scale - 0.5f, 0.0f), msm1);
    float g0 = -1.0f + 2.0f * sy / msm1;
#pragma unroll
    for (int dx = 0; dx < 3; ++dx) {
      int xx = x + dx - 1;
      if (xx < 0 || xx >= H) continue;
      float sx = fminf(fmaxf((xx + 0.5f) * scale - 0.5f, 0.0f), msm1);
      float g1 = -1.0f + 2.0f * sx / msm1;
      conv += w[((c * 2 + 0) * 3 + dy) * 3 + dx] * g0
            + w[((c * 2 + 1) * 3 + dy) * 3 + dx] * g1;
    }
  }
  dst[idx] = src[idx] + conv;
}

// ---------------- unfold(3,1,1) + l2-norm -> split-fp16 (hi, lo) ----------
__global__ void unfold_norm_kernel(const float* __restrict__ src,
                                   _Float16* __restrict__ dhi,
                                   _Float16* __restrict__ dlo) {
  int pos = blockIdx.x;          // 0..2303
  int n = blockIdx.y;
  int y = pos / 48, x = pos - (pos / 48) * 48;
  int tid = threadIdx.x;         // 256
  const float* s = src + (size_t)n * 256 * HW48;
  float v[9];
  float ss = 0.0f;
#pragma unroll
  for (int it = 0; it < 9; ++it) {
    int f = tid + it * 256;
    int c = f / 9, r = f - c * 9;
    int dy = r / 3, dx = r - dy * 3;
    int yy = y + dy - 1, xx = x + dx - 1;
    float val = 0.0f;
    if (yy >= 0 && yy < 48 && xx >= 0 && xx < 48)
      val = s[(c * 48 + yy) * 48 + xx];
    v[it] = val;
    ss += val * val;
  }
  __shared__ float red[256];
  red[tid] = ss;
  __syncthreads();
  for (int ofs = 128; ofs > 0; ofs >>= 1) {
    if (tid < ofs) red[tid] += red[tid + ofs];
    __syncthreads();
  }
  float norm = fmaxf(sqrtf(red[0]), 1e-12f);
  _Float16* dh = dhi + ((size_t)n * HW48 + pos) * (size_t)F9;
  _Float16* dl = dlo + ((size_t)n * HW48 + pos) * (size_t)F9;
#pragma unroll
  for (int it = 0; it < 9; ++it) {
    int f = tid + it * 256;
    float xv = v[it] / norm;
    _Float16 h = (_Float16)xv;
    dh[f] = h;
    dl[f] = (_Float16)(xv - (float)h);
  }
}

// ---------------- per-channel spatial mean ----------------
__global__ void chmean_kernel(const float* __restrict__ src, float* __restrict__ out, int C, int HW) {
  int c = blockIdx.x, n = blockIdx.y;
  const float* s = src + ((size_t)n * C + c) * HW;
  float sum = 0.0f;
  for (int i = threadIdx.x; i < HW; i += blockDim.x) sum += s[i];
  __shared__ float red[256];
  red[threadIdx.x] = sum;
  __syncthreads();
  for (int ofs = 128; ofs > 0; ofs >>= 1) {
    if (threadIdx.x < ofs) red[threadIdx.x] += red[threadIdx.x + ofs];
    __syncthreads();
  }
  if (threadIdx.x == 0) out[n * C + c] = red[0] / (float)HW;
}

// ---------------- global cosine similarity ----------------
__global__ void rglob_kernel(const float* __restrict__ mref, const float* __restrict__ mlr,
                             float* __restrict__ rg) {
  int n = blockIdx.x;
  int tid = threadIdx.x; // 256
  float a = mref[n * 256 + tid];
  float b = mlr[n * 256 + tid];
  __shared__ float raa[256], rbb[256], rab[256];
  raa[tid] = a * a; rbb[tid] = b * b; rab[tid] = a * b;
  __syncthreads();
  for (int ofs = 128; ofs > 0; ofs >>= 1) {
    if (tid < ofs) { raa[tid] += raa[tid + ofs]; rbb[tid] += rbb[tid + ofs]; rab[tid] += rab[tid + ofs]; }
    __syncthreads();
  }
  if (tid == 0) {
    float na = fmaxf(sqrtf(raa[0]), 1e-12f);
    float nb = fmaxf(sqrtf(rbb[0]), 1e-12f);
    rg[n] = rab[0] / (na * nb);
  }
}

// ---------------- dynamic-k selector (JAX partitionable threefry) ----------
__device__ inline unsigned rotl32(unsigned v, int r) { return (v << r) | (v >> (32 - r)); }

__global__ void khard_kernel(const float* __restrict__ k_logits, const float* __restrict__ temp,
                             int* __restrict__ kh) {
  if (threadIdx.x != 0 || blockIdx.x != 0) return;
  const unsigned ksa[3] = {0u, 42u, 0u ^ 42u ^ 0x1BD11BDAu};
  const int R0[4] = {13, 15, 26, 6};
  const int R1[4] = {17, 29, 16, 24};
  float T = temp[0];
  for (int lvl = 0; lvl < 3; ++lvl) {
    int best = 0;
    float bv = -1e30f;
    for (int j = 0; j < 5; ++j) {
      int idx = lvl * 5 + j;
      unsigned x0 = 0u + ksa[0];
      unsigned x1 = (unsigned)idx + ksa[1];
      for (int grp = 0; grp < 5; ++grp) {
        const int* rr = (grp & 1) ? R1 : R0;
        for (int q = 0; q < 4; ++q) { x0 += x1; x1 = rotl32(x1, rr[q]); x1 ^= x0; }
        x0 += ksa[(grp + 1) % 3];
        x1 += ksa[(grp + 2) % 3] + (unsigned)(grp + 1);
      }
      unsigned bb = x0 ^ x1;
      float f = __uint_as_float((bb >> 9) | 0x3f800000u) - 1.0f;
      float u = __fadd_rn(__fmul_rn(f, 1.0f - 1e-6f), 1e-6f);
      u = fmaxf(u, 1e-6f);
      float g = -logf(-logf(u));
      float v = (k_logits[idx] + g) / T;
      if (v > bv) { bv = v; best = j; }
    }
    kh[lvl] = best + 1;
  }
}

// ---------------- split-fp16 MFMA NT GEMM + fused per-tile top-5 -----------
// No R matrix: each block reduces its 128x128 tile of raw acc to per-column
// top-5 (val, global row) and writes tileTop[n][by][bx][col][5].
__global__ __launch_bounds__(256) void gemm_mfma_kernel(
    const _Float16* __restrict__ Ah, const _Float16* __restrict__ Al,
    const _Float16* __restrict__ Bh, const _Float16* __restrict__ Bl,
    float2* __restrict__ tileTop) {
  __shared__ __align__(16) _Float16 As_h[128 * 32];
  __shared__ __align__(16) _Float16 As_l[128 * 32];
  __shared__ __align__(16) _Float16 Bs_h[128 * 32];
  __shared__ __align__(16) _Float16 Bs_l[128 * 32];
  const int n = blockIdx.z;
  const size_t nb = (size_t)n * HW48 * F9;
  const _Float16* Ahp = Ah + nb + (size_t)(blockIdx.y * 128) * F9;
  const _Float16* Alp = Al + nb + (size_t)(blockIdx.y * 128) * F9;
  const _Float16* Bhp = Bh + nb + (size_t)(blockIdx.x * 128) * F9;
  const _Float16* Blp = Bl + nb + (size_t)(blockIdx.x * 128) * F9;
  const int tid = threadIdx.x;
  const int lane = tid & 63, wid = tid >> 6;
  const int wm = (wid >> 1) * 64, wn = (wid & 1) * 64;
  const int r16 = lane & 15, quad = lane >> 4;

  int sgoff[2], sldsb[2];
#pragma unroll
  for (int s = 0; s < 2; ++s) {
    int row = wid * 32 + s * 16 + (lane >> 2);
    int g = (lane & 3) ^ (row & 3) ^ ((row >> 2) & 3);
    sgoff[s] = row * F9 + g * 8;
    sldsb[s] = (wid * 32 + s * 16) * 32;
  }

  floatx4 acc[4][4];
#pragma unroll
  for (int i = 0; i < 4; ++i)
#pragma unroll
    for (int j = 0; j < 4; ++j) acc[i][j] = (floatx4){0.f, 0.f, 0.f, 0.f};

  int fa[4], fb[4];
#pragma unroll
  for (int i = 0; i < 4; ++i) {
    int Ra = wm + i * 16 + r16;
    fa[i] = Ra * 32 + ((quad ^ (Ra & 3) ^ ((Ra >> 2) & 3)) * 8);
    int Rb = wn + i * 16 + r16;
    fb[i] = Rb * 32 + ((quad ^ (Rb & 3) ^ ((Rb >> 2) & 3)) * 8);
  }

  for (int k0 = 0; k0 < F9; k0 += 32) {
    __syncthreads();
#pragma unroll
    for (int s = 0; s < 2; ++s) {
      int go = sgoff[s] + k0;
      gl2lds16(Ahp + go, &As_h[sldsb[s]]);
      gl2lds16(Alp + go, &As_l[sldsb[s]]);
      gl2lds16(Bhp + go, &Bs_h[sldsb[s]]);
      gl2lds16(Blp + go, &Bs_l[sldsb[s]]);
    }
    __syncthreads();
    half8_t ah[4], al[4], bh[4], bl[4];
#pragma unroll
    for (int i = 0; i < 4; ++i) {
      ah[i] = *(const half8_t*)&As_h[fa[i]];
      al[i] = *(const half8_t*)&As_l[fa[i]];
      bh[i] = *(const half8_t*)&Bs_h[fb[i]];
      bl[i] = *(const half8_t*)&Bs_l[fb[i]];
    }
#pragma unroll
    for (int i = 0; i < 4; ++i)
#pragma unroll
      for (int j = 0; j < 4; ++j) {
        acc[i][j] = __builtin_amdgcn_mfma_f32_16x16x32_f16(ah[i], bh[j], acc[i][j], 0, 0, 0);
        acc[i][j] = __builtin_amdgcn_mfma_f32_16x16x32_f16(ah[i], bl[j], acc[i][j], 0, 0, 0);
        acc[i][j] = __builtin_amdgcn_mfma_f32_16x16x32_f16(al[i], bh[j], acc[i][j], 0, 0, 0);
      }
  }

  // ---- fused epilogue: per-column top-5 of raw acc over 128 rows ----
  float* evals = (float*)As_h;   // 256*5*4 B = 5 KB (reuse staging LDS)
  int*   erows = (int*)As_l;     // 5 KB
  float2* tout = tileTop + ((((size_t)n * 18 + blockIdx.y) * 18 + blockIdx.x) * 128) * 5;
  const int rowbase = blockIdx.y * 128 + wm;
  for (int j = 0; j < 4; ++j) {
    float tv[5]; int tr[5];
#pragma unroll
    for (int k = 0; k < 5; ++k) { tv[k] = -3.0e38f; tr[k] = 0x7fffffff; }
#pragma unroll
    for (int i = 0; i < 4; ++i)
#pragma unroll
      for (int r = 0; r < 4; ++r)
        insert5(acc[i][j][r], rowbase + i * 16 + quad * 4 + r, tv, tr);
    __syncthreads();   // all waves done reading LDS (staging or prev pass)
#pragma unroll
    for (int k = 0; k < 5; ++k) {
      evals[tid * 5 + k] = tv[k];
      erows[tid * 5 + k] = tr[k];
    }
    __syncthreads();
    if (tid < 32) {
      int wnq = tid >> 4;        // 0: wn=0 (waves 0,2) / 1: wn=64 (waves 1,3)
      int rr = tid & 15;
      float mv[5]; int mr[5];
#pragma unroll
      for (int k = 0; k < 5; ++k) { mv[k] = -3.0e38f; mr[k] = 0x7fffffff; }
      for (int wsel = 0; wsel < 2; ++wsel) {
        int lbase = (wnq + wsel * 2) * 64 + rr;
        for (int qd = 0; qd < 4; ++qd) {
          int lidx = lbase + qd * 16;
#pragma unroll
          for (int k = 0; k < 5; ++k)
            insert5(evals[lidx * 5 + k], erows[lidx * 5 + k], mv, mr);
        }
      }
      float2* o = tout + (size_t)(wnq * 64 + j * 16 + rr) * 5;
#pragma unroll
      for (int k = 0; k < 5; ++k) o[k] = make_float2(mv[k], __int_as_float(mr[k]));
    }
  }
}

// ---------------- merge per-tile top-5 across 18 row-tiles -> WP -----------
__global__ void topk_merge_kernel(const float2* __restrict__ tileTop,
                                  const float* __restrict__ rg, const float* __restrict__ gwp,
                                  float2* __restrict__ WP) {
  int t = blockIdx.x * 256 + threadIdx.x;
  if (t >= 2 * HW48) return;
  int n = t / HW48, q = t % HW48;
  int bx = q >> 7, c = q & 127;
  float mv[5]; int mr[5];
#pragma unroll
  for (int k = 0; k < 5; ++k) { mv[k] = -3.0e38f; mr[k] = 0x7fffffff; }
  for (int by = 0; by < 18; ++by) {
    const float2* src = tileTop + ((((size_t)n * 18 + by) * 18 + bx) * 128 + c) * 5;
#pragma unroll
    for (int k = 0; k < 5; ++k) {
      float2 e = src[k];
      insert5(e.x, __float_as_int(e.y), mv, mr);
    }
  }
  float gw = gwp[0], base = gw * rg[n], w1 = 1.0f - gw;
  float2* o = WP + ((size_t)n * HW48 + q) * 5;
#pragma unroll
  for (int k = 0; k < 5; ++k) {
    float val = w1 * mv[k] + base;
    int p = mr[k];
    o[k] = make_float2(1.0f / (1.0f + expf(-val)), __int_as_float(((p % 48) << 16) | (p / 48)));
  }
}

// ---------------- fused transfer + fold (per-channel, LDS candidate cache) -
__global__ __launch_bounds__(256) void transfer_kernel(const float* __restrict__ refenc,
                                                       const float2* __restrict__ WP,
                                                       const int* __restrict__ khp,
                                                       float* __restrict__ out, int C, int s,
                                                       int pad, int lvl, float kk, int total) {
  __shared__ float2 wp_s[1920];  // up to 8 qh-rows x 48 x 5
  const int Hout = 48 * s;
  const int HH = Hout * Hout;
  const int idx = blockIdx.x * 256 + threadIdx.x;
  const int sp0 = (blockIdx.x * 256) % HH;
  const int Y0 = sp0 / Hout, Y1 = (sp0 + 255) / Hout;
  const int qh0 = max(0, (Y0 + pad) / s - 2);
  const int qh1 = min(47, (Y1 + pad) / s);
  const int nload = (qh1 - qh0 + 1) * 240;
  const int nblk = (blockIdx.x * 256) / (C * HH);
  const float2* WPn = WP + (size_t)nblk * HW48 * 5 + (size_t)qh0 * 240;
  for (int i = threadIdx.x; i < nload; i += 256) wp_s[i] = WPn[i];
  __syncthreads();
  if (idx >= total) return;

  const int sp = idx % HH;
  const int X = sp % Hout, Y = sp / Hout;
  const int c = (idx / HH) % C;
  const int n = idx / (C * HH);
  const int kh = khp[lvl];
  const int Yp = Y + pad, Xp = X + pad;
  const int Qy = Yp / s, Qx = Xp / s;
  const float* rf = refenc + ((size_t)n * C + c) * (size_t)HH;
  float acc = 0.0f;
  for (int t = 0; t < 3; ++t) {
    int qh = Qy - t;
    if (qh < 0 || qh >= 48) continue;
    int i = Yp - s * qh;            // kernel row offset in [0,3s)
    for (int u = 0; u < 3; ++u) {
      int qw = Qx - u;
      if (qw < 0 || qw >= 48) continue;
      int j = Xp - s * qw;
      int base = ((qh - qh0) * 48 + qw) * 5;
      for (int m = 0; m < kh; ++m) {
        float2 wp = wp_s[base + m];
        float wgt = wp.x;
        int pxy = __float_as_int(wp.y);
        int ph = pxy & 0xffff, pw = pxy >> 16;
        int yy = ph * s + i - pad;
        int xx = pw * s + j - pad;
        if (yy >= 0 && yy < Hout && xx >= 0 && xx < Hout)
          acc = fmaf(wgt, rf[yy * Hout + xx], acc);
      }
    }
  }
  out[idx] = acc / kk;
}

// ---------------- SE: mlp + scale ----------------
__global__ void se_mlp_kernel(const float* __restrict__ means, const float* __restrict__ w1,
                              const float* __restrict__ b1, const float* __restrict__ w2,
                              const float* __restrict__ b2, float* __restrict__ scale,
                              int C, int R) {
  int n = blockIdx.x;
  int tid = threadIdx.x;
  __shared__ float ym[256];
  __shared__ float h1[16];
  if (tid < C) ym[tid] = means[n * C + tid];
  __syncthreads();
  if (tid < R) {
    float s = b1[tid];
    for (int c = 0; c < C; ++c) s += ym[c] * w1[tid * C + c];
    h1[tid] = fmaxf(s, 0.0f);
  }
  __syncthreads();
  if (tid < C) {
    float s = b2[tid];
    for (int r = 0; r < R; ++r) s += h1[r] * w2[tid * R + r];
    scale[n * C + tid] = 1.0f / (1.0f + expf(-s));
  }
}

__global__ void se_scale_kernel(float* __restrict__ T, const float* __restrict__ scale,
                                int C, int HW, int total) {
  int idx = blockIdx.x * blockDim.x + threadIdx.x;
  if (idx >= total) return;
  int c = (idx / HW) % C;
  int n = idx / (C * HW);
  T[idx] *= scale[n * C + c];
}

extern "C" void kernel_launch(void* const* d_in, const int* in_sizes, int n_in,
                              void* d_out, int out_size, void* d_ws, size_t ws_size,
                              hipStream_t stream) {
  const float* lrsr   = (const float*)d_in[0];
  const float* refsr  = (const float*)d_in[1];
  const float* ref1   = (const float*)d_in[2];
  const float* ref2   = (const float*)d_in[3];
  const float* ref3   = (const float*)d_in[4];
  const float* klog   = (const float*)d_in[5];
  const float* temp   = (const float*)d_in[6];
  const float* gwp    = (const float*)d_in[7];
  const float* pos_w1 = (const float*)d_in[8];
  const float* pos_b1 = (const float*)d_in[9];
  const float* pos_w2 = (const float*)d_in[10];
  const float* pos_b2 = (const float*)d_in[11];
  const float* pos_w3 = (const float*)d_in[12];
  const float* pos_b3 = (const float*)d_in[13];
  const float* se1_w1 = (const float*)d_in[14];
  const float* se1_b1 = (const float*)d_in[15];
  const float* se1_w2 = (const float*)d_in[16];
  const float* se1_b2 = (const float*)d_in[17];
  const float* se2_w1 = (const float*)d_in[18];
  const float* se2_b1 = (const float*)d_in[19];
  const float* se2_w2 = (const float*)d_in[20];
  const float* se2_b2 = (const float*)d_in[21];
  const float* se3_w1 = (const float*)d_in[22];
  const float* se3_b1 = (const float*)d_in[23];
  const float* se3_w2 = (const float*)d_in[24];
  const float* se3_b2 = (const float*)d_in[25];
  float* out = (float*)d_out;
  float* ws = (float*)d_ws;

  // workspace layout (float-indexed)
  float* refsr_enc = ws + 0;                        // 1,179,648
  float* ref3_enc  = ws + 1179648;                  // 1,179,648
  float* ref2_enc  = ws + 2359296;                  // 2,359,296
  float* ref1_enc  = ws + 4718592;                  // 4,718,592
  _Float16* Ah_hi  = (_Float16*)(ws + 9437184);     // 10,616,832 halves
  _Float16* Ah_lo  = (_Float16*)(ws + 14745600);
  _Float16* Bh_hi  = (_Float16*)(ws + 20054016);
  _Float16* Bh_lo  = (_Float16*)(ws + 25362432);
  float2* tileTop  = (float2*)(ws + 30670848);      // 414,720 float2 (~3.3 MB)
  float2* WP       = (float2*)(ws + 41287680);      // 23,040 float2
  float* mref      = ws + 41333760;                 // 512
  float* mlr       = ws + 41334272;                 // 512
  float* rg        = ws + 41334784;                 // 2
  int*   kh        = (int*)(ws + 41334788);         // 3
  float* semean    = ws + 41334792;                 // 512
  float* sescale   = ws + 41335304;                 // 512

  // output segments: (T3, T2, T1)
  float* T3 = out;
  float* T2 = out + 1179648;
  float* T1 = out + 3538944;

  // 1) position encodings
  enc_kernel<<<4608, 256, 0, stream>>>(refsr, pos_w3, pos_b3, refsr_enc, 256, 48, 64, 1179648);
  enc_kernel<<<4608, 256, 0, stream>>>(ref3, pos_w3, pos_b3, ref3_enc, 256, 48, 64, 1179648);
  enc_kernel<<<9216, 256, 0, stream>>>(ref2, pos_w2, pos_b2, ref2_enc, 128, 96, 128, 2359296);
  enc_kernel<<<18432, 256, 0, stream>>>(ref1, pos_w1, pos_b1, ref1_enc, 64, 192, 256, 4718592);

  // 2) unfold + l2norm -> split fp16 (A: encoded ref, B: raw lrsr)
  unfold_norm_kernel<<<dim3(2304, 2), 256, 0, stream>>>(refsr_enc, Ah_hi, Ah_lo);
  unfold_norm_kernel<<<dim3(2304, 2), 256, 0, stream>>>(lrsr, Bh_hi, Bh_lo);

  // 3) global similarity + k-selector
  chmean_kernel<<<dim3(256, 2), 256, 0, stream>>>(refsr_enc, mref, 256, 2304);
  chmean_kernel<<<dim3(256, 2), 256, 0, stream>>>(lrsr, mlr, 256, 2304);
  rglob_kernel<<<2, 256, 0, stream>>>(mref, mlr, rg);
  khard_kernel<<<1, 64, 0, stream>>>(klog, temp, kh);

  // 4) correlation GEMM with fused per-tile top-5 (no R matrix)
  gemm_mfma_kernel<<<dim3(18, 18, 2), 256, 0, stream>>>(Ah_hi, Ah_lo, Bh_hi, Bh_lo, tileTop);

  // 5) merge row-tiles -> {sigmoid(R), packed pw|ph}
  topk_merge_kernel<<<18, 256, 0, stream>>>(tileTop, rg, gwp, WP);

  // 6) transfer + fold, per-channel gather with LDS candidate cache
  transfer_kernel<<<4608, 256, 0, stream>>>(ref3_enc, WP, kh, T3, 256, 1, 1, 0, 9.0f, 1179648);
  transfer_kernel<<<9216, 256, 0, stream>>>(ref2_enc, WP, kh, T2, 128, 2, 2, 1, 36.0f, 2359296);
  transfer_kernel<<<18432, 256, 0, stream>>>(ref1_enc, WP, kh, T1, 64, 4, 4, 2, 144.0f, 4718592);

  // 7) SE per level (means -> tiny MLP -> in-place scale)
  chmean_kernel<<<dim3(256, 2), 256, 0, stream>>>(T3, semean, 256, 2304);
  se_mlp_kernel<<<2, 256, 0, stream>>>(semean, se3_w1, se3_b1, se3_w2, se3_b2, sescale, 256, 16);
  se_scale_kernel<<<4608, 256, 0, stream>>>(T3, sescale, 256, 2304, 1179648);

  chmean_kernel<<<dim3(128, 2), 256, 0, stream>>>(T2, semean, 128, 9216);
  se_mlp_kernel<<<2, 256, 0, stream>>>(semean, se2_w1, se2_b1, se2_w2, se2_b2, sescale, 128, 8);
  se_scale_kernel<<<9216, 256, 0, stream>>>(T2, sescale, 128, 9216, 2359296);

  chmean_kernel<<<dim3(64, 2), 256, 0, stream>>>(T1, semean, 64, 36864);
  se_mlp_kernel<<<2, 256, 0, stream>>>(semean, se1_w1, se1_b1, se1_w2, se1_b2, sescale, 64, 4);
  se_scale_kernel<<<18432, 256, 0, stream>>>(T1, sescale, 64, 36864, 4718592);
}